// Round 1
// baseline (439.608 us; speedup 1.0000x reference)
//
#include <hip/hip_runtime.h>
#include <math.h>

// Problem constants (match reference setup_inputs)
#define B_    8
#define L_    4096
#define D_    2048
#define D2_   4096      // 2*D
#define T_    128
#define LN_EPS_ 1e-5f

#define LCHUNK 128      // L rows per pool block     -> 4096/128 = 32 chunks
#define KC1    64       // k-chunk for gemv1 (red dim D_=2048 -> 32 chunks)
#define KC2    64       // j-chunk for gemv2 (red dim D2_=4096 -> 64 chunks)

// ---------------- K0: per-row mask counts ----------------
__global__ void k_masks(const float* __restrict__ tmask,
                        const float* __restrict__ cmask,
                        float* __restrict__ cnt, float* __restrict__ tcnt) {
  const int b = blockIdx.x;
  const int tid = threadIdx.x;           // 256 threads
  float sc = 0.f, st = 0.f;
  for (int i = tid; i < L_; i += 256) {
    sc += cmask[b * L_ + i];
    st += tmask[b * L_ + i];
  }
  __shared__ float sC[256], sT[256];
  sC[tid] = sc; sT[tid] = st;
  __syncthreads();
  for (int off = 128; off > 0; off >>= 1) {
    if (tid < off) { sC[tid] += sC[tid + off]; sT[tid] += sT[tid + off]; }
    __syncthreads();
  }
  if (tid == 0) { cnt[b] = sC[0]; tcnt[b] = sT[0]; }
}

// ---------------- K1: pool (column sum over L) ----------------
// grid: (32 L-chunks, 2 d-blocks, 8 batch), block 256; each thread float4 of d.
__global__ void k_pool(const float* __restrict__ x, float* __restrict__ csum) {
  const int lc = blockIdx.x;
  const int db = blockIdx.y;
  const int b  = blockIdx.z;
  const int d  = db * 1024 + threadIdx.x * 4;
  const float* p = x + (size_t)b * L_ * D_ + (size_t)lc * LCHUNK * D_ + d;
  float ax = 0.f, ay = 0.f, az = 0.f, aw = 0.f;
  #pragma unroll 8
  for (int l = 0; l < LCHUNK; ++l) {
    const float4 v = *reinterpret_cast<const float4*>(p + (size_t)l * D_);
    ax += v.x; ay += v.y; az += v.z; aw += v.w;
  }
  float* o = csum + b * D_ + d;
  atomicAdd(o + 0, ax); atomicAdd(o + 1, ay);
  atomicAdd(o + 2, az); atomicAdd(o + 3, aw);
}

// ---------------- K2: h_pre = ctx_sum @ W1 (divide by cnt deferred) --------
// grid: (16 j-blocks of 256 cols, 32 k-chunks), block 256.
__global__ void k_gemv1(const float* __restrict__ S,     // ctx_sum [B][D]
                        const float* __restrict__ W1,    // [D][2D]
                        float* __restrict__ h_pre) {     // [B][2D] (zeroed)
  const int j  = blockIdx.x * 256 + threadIdx.x;
  const int k0 = blockIdx.y * KC1;
  __shared__ float s[B_][KC1];
  for (int i = threadIdx.x; i < B_ * KC1; i += 256) {
    const int bb = i / KC1, kk = i % KC1;
    s[bb][kk] = S[bb * D_ + k0 + kk];
  }
  __syncthreads();
  float acc[B_];
  #pragma unroll
  for (int bb = 0; bb < B_; ++bb) acc[bb] = 0.f;
  const float* w = W1 + (size_t)k0 * D2_ + j;
  #pragma unroll 4
  for (int k = 0; k < KC1; ++k) {
    const float wv = w[(size_t)k * D2_];
    #pragma unroll
    for (int bb = 0; bb < B_; ++bb) acc[bb] += s[bb][k] * wv;
  }
  #pragma unroll
  for (int bb = 0; bb < B_; ++bb) atomicAdd(&h_pre[bb * D2_ + j], acc[bb]);
}

// ---------------- K3: h = GELU(h_pre/cnt + b1); hn = LN(h)*gamma+beta ------
// grid: 8 rows, block 1024 (4 elems/thread as float4)
__global__ void k_gelu_ln(const float* __restrict__ h_pre,
                          const float* __restrict__ cnt,
                          const float* __restrict__ b1,
                          const float* __restrict__ gamma,
                          const float* __restrict__ beta,
                          float* __restrict__ hn) {
  const int b = blockIdx.x;
  const int tid = threadIdx.x;           // 1024
  const float c = cnt[b];
  const float scale = (c > 0.f) ? (1.f / fmaxf(c, 1.f)) : 0.f;
  const int j = tid * 4;
  float4 hp = *reinterpret_cast<const float4*>(h_pre + (size_t)b * D2_ + j);
  float4 bb = *reinterpret_cast<const float4*>(b1 + j);
  float g[4];
  {
    const float v0 = hp.x * scale + bb.x;
    const float v1 = hp.y * scale + bb.y;
    const float v2 = hp.z * scale + bb.z;
    const float v3 = hp.w * scale + bb.w;
    g[0] = 0.5f * v0 * (1.f + erff(v0 * 0.70710678118654752f));
    g[1] = 0.5f * v1 * (1.f + erff(v1 * 0.70710678118654752f));
    g[2] = 0.5f * v2 * (1.f + erff(v2 * 0.70710678118654752f));
    g[3] = 0.5f * v3 * (1.f + erff(v3 * 0.70710678118654752f));
  }
  float lsum = g[0] + g[1] + g[2] + g[3];
  float lsq  = g[0]*g[0] + g[1]*g[1] + g[2]*g[2] + g[3]*g[3];
  __shared__ float sS[1024], sQ[1024];
  sS[tid] = lsum; sQ[tid] = lsq;
  __syncthreads();
  for (int off = 512; off > 0; off >>= 1) {
    if (tid < off) { sS[tid] += sS[tid + off]; sQ[tid] += sQ[tid + off]; }
    __syncthreads();
  }
  const float mu  = sS[0] * (1.f / D2_);
  const float var = sQ[0] * (1.f / D2_) - mu * mu;
  const float rs  = rsqrtf(var + LN_EPS_);
  float4 gm = *reinterpret_cast<const float4*>(gamma + j);
  float4 bt = *reinterpret_cast<const float4*>(beta + j);
  float4 o;
  o.x = (g[0] - mu) * rs * gm.x + bt.x;
  o.y = (g[1] - mu) * rs * gm.y + bt.y;
  o.z = (g[2] - mu) * rs * gm.z + bt.z;
  o.w = (g[3] - mu) * rs * gm.w + bt.w;
  *reinterpret_cast<float4*>(hn + (size_t)b * D2_ + j) = o;
}

// ---------------- K4: out_pre = hn @ W2 (b2 added in scatter) --------------
// grid: (8 d-blocks of 256, 64 j-chunks), block 256.
__global__ void k_gemv2(const float* __restrict__ HN,    // [B][2D]
                        const float* __restrict__ W2,    // [2D][D]
                        float* __restrict__ out_pre) {   // [B][D] (zeroed)
  const int d  = blockIdx.x * 256 + threadIdx.x;
  const int j0 = blockIdx.y * KC2;
  __shared__ float s[B_][KC2];
  for (int i = threadIdx.x; i < B_ * KC2; i += 256) {
    const int bb = i / KC2, jj = i % KC2;
    s[bb][jj] = HN[bb * D2_ + j0 + jj];
  }
  __syncthreads();
  float acc[B_];
  #pragma unroll
  for (int bb = 0; bb < B_; ++bb) acc[bb] = 0.f;
  const float* w = W2 + (size_t)j0 * D_ + d;
  #pragma unroll 4
  for (int k = 0; k < KC2; ++k) {
    const float wv = w[(size_t)k * D_];
    #pragma unroll
    for (int bb = 0; bb < B_; ++bb) acc[bb] += s[bb][k] * wv;
  }
  #pragma unroll
  for (int bb = 0; bb < B_; ++bb) atomicAdd(&out_pre[bb * D_ + d], acc[bb]);
}

// ---------------- K5: scatter into [B][T][D] with zero padding -------------
__global__ void k_scatter(const float* __restrict__ out_pre,
                          const float* __restrict__ b2,
                          const float* __restrict__ tcnt,
                          float* __restrict__ out) {
  const size_t idx = ((size_t)blockIdx.x * 256 + threadIdx.x) * 4;
  const int d  = (int)(idx % D_);
  const int bt = (int)(idx / D_);
  const int t  = bt % T_;
  const int b  = bt / T_;
  float4 v = make_float4(0.f, 0.f, 0.f, 0.f);
  if (t < (int)(tcnt[b] + 0.5f)) {
    const float4 op = *reinterpret_cast<const float4*>(out_pre + b * D_ + d);
    const float4 bv = *reinterpret_cast<const float4*>(b2 + d);
    v = make_float4(op.x + bv.x, op.y + bv.y, op.z + bv.z, op.w + bv.w);
  }
  *reinterpret_cast<float4*>(out + idx) = v;
}

extern "C" void kernel_launch(void* const* d_in, const int* in_sizes, int n_in,
                              void* d_out, int out_size, void* d_ws, size_t ws_size,
                              hipStream_t stream) {
  const float* context_repr = (const float*)d_in[0];
  const float* target_mask  = (const float*)d_in[1];
  const float* context_mask = (const float*)d_in[2];
  const float* W1    = (const float*)d_in[3];
  const float* b1    = (const float*)d_in[4];
  const float* gamma = (const float*)d_in[5];
  const float* beta  = (const float*)d_in[6];
  const float* W2    = (const float*)d_in[7];
  const float* b2    = (const float*)d_in[8];
  float* out = (float*)d_out;

  // Workspace layout (floats)
  float* ws       = (float*)d_ws;
  float* ctx_sum  = ws;                        // 8*2048   = 16384
  float* cnt      = ctx_sum + B_ * D_;         // 8
  float* tcnt     = cnt + B_;                  // 8
  float* h_pre    = tcnt + B_;                 // 8*4096   = 32768
  float* hn       = h_pre + B_ * D2_;          // 8*4096   = 32768
  float* out_pre  = hn + B_ * D2_;             // 8*2048   = 16384
  const size_t ws_used = (size_t)(B_*D_ + 2*B_ + 2*B_*D2_ + B_*D_) * sizeof(float);

  hipMemsetAsync(d_ws, 0, ws_used, stream);

  k_masks<<<dim3(B_), dim3(256), 0, stream>>>(target_mask, context_mask, cnt, tcnt);

  k_pool<<<dim3(L_ / LCHUNK, D_ / 1024, B_), dim3(256), 0, stream>>>(context_repr, ctx_sum);

  k_gemv1<<<dim3(D2_ / 256, D_ / KC1), dim3(256), 0, stream>>>(ctx_sum, W1, h_pre);

  k_gelu_ln<<<dim3(B_), dim3(1024), 0, stream>>>(h_pre, cnt, b1, gamma, beta, hn);

  k_gemv2<<<dim3(D_ / 256, D2_ / KC2), dim3(256), 0, stream>>>(hn, W2, out_pre);

  const int n_out4 = out_size / 4;             // B*T*D / 4
  k_scatter<<<dim3((n_out4 + 255) / 256), dim3(256), 0, stream>>>(out_pre, b2, tcnt, out);
}